// Round 19
// baseline (389.385 us; speedup 1.0000x reference)
//
#include <hip/hip_runtime.h>
#include <hip/hip_bf16.h>
#include <stdint.h>

#define NN 10000
#define NE 160000
#define INF 256
#define CH 512
#define NL 1440
#define MPAN 158   // ceil(10000/64) A panels (64-row)

typedef __bf16 bf16;
typedef __attribute__((ext_vector_type(8))) bf16 bf16x8;
typedef __attribute__((ext_vector_type(4))) float f32x4;

// A tiled layout: [panel(64 rows)][chunk(32 k')][g=4][row=64][j=8] (2048 elem/chunk)
// B tiled layout: [panel(128 cols)][chunk(32 k')][g=4][col=128][j=8] (4096 elem/chunk)
// Pure-bf16 associativity form: h' = relu([h | hagg] @ [V | W] + b)
//   mid: A 32 chunks (h 0-15, hagg 16-31);  L1: A 16 chunks (x 0-7, xagg 8-15).
// All GEMMs: 64r x 128c tile, BK=64 (2 chunks/iter), 48KB LDS, 3 blocks/CU.
// Mid gathers: 1 slice x 512 channels, uint4 (8 ch, 16B) per lane — one wave
// reads a node's full row per edge; single edge-list traversal per layer.

__device__ __forceinline__ void gload16(const void* g, const void* l) {
    auto gp = reinterpret_cast<const __attribute__((address_space(1))) uint32_t*>(
        reinterpret_cast<uintptr_t>(g));
    auto lp = reinterpret_cast<__attribute__((address_space(3))) uint32_t*>(
        reinterpret_cast<uintptr_t>(l));
    __builtin_amdgcn_global_load_lds(gp, lp, 16, 0, 0);
}

// ---------------- graph prep ----------------
__global__ void deg_kernel(const int* __restrict__ src, const int* __restrict__ dst,
                           int* __restrict__ deg_out, int* __restrict__ deg_in) {
    int e = blockIdx.x * 256 + threadIdx.x;
    if (e < NE) {
        atomicAdd(&deg_out[src[e]], 1);
        atomicAdd(&deg_in[dst[e]], 1);
    }
}

__global__ __launch_bounds__(1024) void scan_kernel(const int* __restrict__ deg,
                                                    int* __restrict__ offsets,
                                                    int* __restrict__ cursor) {
    __shared__ int sums[1024];
    const int PER = 10;
    int tid = threadIdx.x;
    int base = tid * PER;
    int local[PER];
    int s = 0;
    #pragma unroll
    for (int i = 0; i < PER; i++) {
        int v = (base + i < NN) ? deg[base + i] : 0;
        local[i] = s;
        s += v;
    }
    sums[tid] = s;
    __syncthreads();
    for (int off = 1; off < 1024; off <<= 1) {
        int v = (tid >= off) ? sums[tid - off] : 0;
        __syncthreads();
        sums[tid] += v;
        __syncthreads();
    }
    int prev = (tid > 0) ? sums[tid - 1] : 0;
    #pragma unroll
    for (int i = 0; i < PER; i++) {
        if (base + i < NN) {
            int o = prev + local[i];
            offsets[base + i] = o;
            cursor[base + i] = o;
        }
    }
    if (tid == 0) offsets[NN] = sums[1023];
}

__global__ void csr_kernel(const int* __restrict__ src, const int* __restrict__ dst,
                           const int* __restrict__ deg_out, const int* __restrict__ deg_in,
                           int* __restrict__ cursor, int2* __restrict__ edge_pk) {
    int e = blockIdx.x * 256 + threadIdx.x;
    if (e < NE) {
        int s = src[e], d = dst[e];
        float dw = (float)max(deg_out[s], 1) * (float)max(deg_in[d], 1);
        float w = rsqrtf(dw);
        int pos = atomicAdd(&cursor[s], 1);
        edge_pk[pos] = make_int2(d, __float_as_int(w));
    }
}

// -------- fused conversions: x->(xb,A_L1) | V1W1 | VkWk | Wd --------
__global__ void conv_fused(const float* __restrict__ x, bf16* __restrict__ xb,
                           bf16* __restrict__ A_L1,
                           const float* __restrict__ V1, const float* __restrict__ W1,
                           bf16* __restrict__ B1t,
                           const float* __restrict__ Vk, const float* __restrict__ Wk,
                           bf16* __restrict__ Bkt,
                           const float* __restrict__ Wd, bf16* __restrict__ Wdt) {
    int b = blockIdx.x;
    int tid = threadIdx.x;
    if (b < 1250) {
        int idx = b * 256 + tid;
        if (idx >= NN * 32) return;
        int m = idx >> 5;
        int k8 = (idx & 31) * 8;
        const float* src = x + (size_t)m * INF + k8;
        float4 v0 = *(const float4*)src;
        float4 v1 = *(const float4*)(src + 4);
        bf16x8 o;
        o[0] = (bf16)v0.x; o[1] = (bf16)v0.y; o[2] = (bf16)v0.z; o[3] = (bf16)v0.w;
        o[4] = (bf16)v1.x; o[5] = (bf16)v1.y; o[6] = (bf16)v1.z; o[7] = (bf16)v1.w;
        *(bf16x8*)&xb[(size_t)idx * 8] = o;
        int panel = m >> 6, row = m & 63;
        int c = k8 >> 5, g = (k8 & 31) >> 3;
        *(bf16x8*)&A_L1[((size_t)panel * 16 + c) * 2048 + g * 512 + row * 8] = o;
    } else if (b < 1314) {
        int idx = (b - 1250) * 256 + tid;
        if (idx >= 512 * 32) return;
        int k8 = (idx >> 9) * 8;
        int n = idx & 511;
        bf16x8 vv, ww;
        #pragma unroll
        for (int j = 0; j < 8; j++) {
            vv[j] = (bf16)V1[(size_t)(k8 + j) * 512 + n];
            ww[j] = (bf16)W1[(size_t)(k8 + j) * 512 + n];
        }
        int panel = n >> 7, row = n & 127;
        int c = k8 >> 5, g = (k8 & 31) >> 3;
        size_t base = (size_t)panel * 16 * 4096 + g * 1024 + row * 8;
        *(bf16x8*)&B1t[base + (size_t)c * 4096] = vv;
        *(bf16x8*)&B1t[base + (size_t)(8 + c) * 4096] = ww;
    } else if (b < 2082) {
        int bb = b - 1314;
        int z = bb >> 7;
        int idx = (bb & 127) * 256 + tid;
        if (idx >= 512 * 64) return;
        const float* V = Vk + (size_t)z * CH * 512;
        const float* W = Wk + (size_t)z * CH * 512;
        bf16* out = Bkt + (size_t)z * 4 * 32 * 4096;
        int k8 = (idx >> 9) * 8;
        int n = idx & 511;
        bf16x8 vv, ww;
        #pragma unroll
        for (int j = 0; j < 8; j++) {
            vv[j] = (bf16)V[(size_t)(k8 + j) * 512 + n];
            ww[j] = (bf16)W[(size_t)(k8 + j) * 512 + n];
        }
        int panel = n >> 7, row = n & 127;
        int c = k8 >> 5, g = (k8 & 31) >> 3;
        size_t base = (size_t)panel * 32 * 4096 + g * 1024 + row * 8;
        *(bf16x8*)&out[base + (size_t)c * 4096] = vv;
        *(bf16x8*)&out[base + (size_t)(16 + c) * 4096] = ww;
    } else {
        int idx = (b - 2082) * 256 + tid;
        if (idx >= NL * 64) return;
        int k8 = (idx / NL) * 8;
        int n = idx % NL;
        bf16x8 hi;
        #pragma unroll
        for (int j = 0; j < 8; j++) hi[j] = (bf16)Wd[(size_t)(k8 + j) * NL + n];
        int panel = n >> 7, row = n & 127;
        int c = k8 >> 5, g = (k8 & 31) >> 3;
        size_t base = ((size_t)panel * 16) * 4096 + g * 1024 + row * 8;
        *(bf16x8*)&Wdt[base + (size_t)c * 4096] = hi;
    }
}

// ---- L1 gather (unchanged): 2 slices x 128 ch, u32 (2 ch) per lane ----
__global__ __launch_bounds__(256) void gather_agg(
    const uint32_t* __restrict__ h32,
    const int* __restrict__ offsets,
    const int2* __restrict__ edge_pk,
    bf16* __restrict__ outA,
    int CHU, int SLOG, int CBASE, int PANCH) {
    int p = blockIdx.x;
    int slice = p & ((1 << SLOG) - 1);
    int grp = p >> SLOG;
    int wid = threadIdx.x >> 6;
    int lane = threadIdx.x & 63;
    int u = grp * 4 + wid;
    if (u >= NN) return;
    int c = slice * 128 + lane * 2;
    int cu = (slice << 6) + lane;

    int beg = offsets[u], end = offsets[u + 1];
    float a0 = 0.f, a1 = 0.f;
    int e = beg;
    for (; e + 7 < end; e += 8) {
        int2 pk[8];
        uint32_t qq[8];
        #pragma unroll
        for (int k = 0; k < 8; k++) pk[k] = edge_pk[e + k];
        #pragma unroll
        for (int k = 0; k < 8; k++) qq[k] = h32[pk[k].x * CHU + cu];
        #pragma unroll
        for (int k = 0; k < 8; k++) {
            float wt = __int_as_float(pk[k].y);
            a0 += wt * __uint_as_float(qq[k] << 16);
            a1 += wt * __uint_as_float(qq[k] & 0xffff0000u);
        }
    }
    for (; e + 3 < end; e += 4) {
        int2 pk[4];
        uint32_t qq[4];
        #pragma unroll
        for (int k = 0; k < 4; k++) pk[k] = edge_pk[e + k];
        #pragma unroll
        for (int k = 0; k < 4; k++) qq[k] = h32[pk[k].x * CHU + cu];
        #pragma unroll
        for (int k = 0; k < 4; k++) {
            float wt = __int_as_float(pk[k].y);
            a0 += wt * __uint_as_float(qq[k] << 16);
            a1 += wt * __uint_as_float(qq[k] & 0xffff0000u);
        }
    }
    for (; e < end; e++) {
        int2 pe = edge_pk[e];
        uint32_t qv = h32[pe.x * CHU + cu];
        float wt = __int_as_float(pe.y);
        a0 += wt * __uint_as_float(qv << 16);
        a1 += wt * __uint_as_float(qv & 0xffff0000u);
    }

    bf16 h0 = (bf16)a0, h1 = (bf16)a1;
    int row = u & 63, panel = u >> 6;
    int ch = CBASE + (c >> 5), g = (c >> 3) & 3, j = c & 7;
    size_t base = (size_t)panel * PANCH * 2048 + (size_t)ch * 2048 + g * 512 + row * 8 + j;
    uint32_t hw = (uint32_t)__builtin_bit_cast(uint16_t, h0) |
                  ((uint32_t)__builtin_bit_cast(uint16_t, h1) << 16);
    *(uint32_t*)&outA[base] = hw;
}

// ---- mid gather: 1 slice x 512 channels, uint4 (8 ch, 16B) per lane ----
// One wave covers a node's full 1KB row per edge; single edge traversal per layer.
__global__ __launch_bounds__(256) void gather_agg8(
    const uint4* __restrict__ h128,  // row-major bf16 pairs, 64 uint4 per row
    const int* __restrict__ offsets,
    const int2* __restrict__ edge_pk,
    bf16* __restrict__ outA) {       // 32-chunk panels, hagg at chunks 16..31
    int grp = blockIdx.x;
    int wid = threadIdx.x >> 6;
    int lane = threadIdx.x & 63;
    int u = grp * 4 + wid;
    if (u >= NN) return;
    int c = lane * 8;                // 8 consecutive channels

    int beg = offsets[u], end = offsets[u + 1];
    float a0 = 0.f, a1 = 0.f, a2 = 0.f, a3 = 0.f;
    float a4 = 0.f, a5 = 0.f, a6 = 0.f, a7 = 0.f;
    int e = beg;
    for (; e + 3 < end; e += 4) {
        int2 pk[4];
        uint4 qq[4];
        #pragma unroll
        for (int k = 0; k < 4; k++) pk[k] = edge_pk[e + k];
        #pragma unroll
        for (int k = 0; k < 4; k++) qq[k] = h128[pk[k].x * 64 + lane];
        #pragma unroll
        for (int k = 0; k < 4; k++) {
            float wt = __int_as_float(pk[k].y);
            a0 += wt * __uint_as_float(qq[k].x << 16);
            a1 += wt * __uint_as_float(qq[k].x & 0xffff0000u);
            a2 += wt * __uint_as_float(qq[k].y << 16);
            a3 += wt * __uint_as_float(qq[k].y & 0xffff0000u);
            a4 += wt * __uint_as_float(qq[k].z << 16);
            a5 += wt * __uint_as_float(qq[k].z & 0xffff0000u);
            a6 += wt * __uint_as_float(qq[k].w << 16);
            a7 += wt * __uint_as_float(qq[k].w & 0xffff0000u);
        }
    }
    for (; e < end; e++) {
        int2 pe = edge_pk[e];
        uint4 qv = h128[pe.x * 64 + lane];
        float wt = __int_as_float(pe.y);
        a0 += wt * __uint_as_float(qv.x << 16);
        a1 += wt * __uint_as_float(qv.x & 0xffff0000u);
        a2 += wt * __uint_as_float(qv.y << 16);
        a3 += wt * __uint_as_float(qv.y & 0xffff0000u);
        a4 += wt * __uint_as_float(qv.z << 16);
        a5 += wt * __uint_as_float(qv.z & 0xffff0000u);
        a6 += wt * __uint_as_float(qv.w << 16);
        a7 += wt * __uint_as_float(qv.w & 0xffff0000u);
    }

    bf16 h0 = (bf16)a0, h1 = (bf16)a1, h2 = (bf16)a2, h3 = (bf16)a3;
    bf16 h4 = (bf16)a4, h5 = (bf16)a5, h6 = (bf16)a6, h7 = (bf16)a7;
    int row = u & 63, panel = u >> 6;
    int ch = 16 + (c >> 5), g = (c >> 3) & 3;   // j = 0 (full 8-group per lane)
    size_t base = (size_t)panel * 32 * 2048 + (size_t)ch * 2048 + g * 512 + row * 8;
    uint4 o;
    o.x = (uint32_t)__builtin_bit_cast(uint16_t, h0) |
          ((uint32_t)__builtin_bit_cast(uint16_t, h1) << 16);
    o.y = (uint32_t)__builtin_bit_cast(uint16_t, h2) |
          ((uint32_t)__builtin_bit_cast(uint16_t, h3) << 16);
    o.z = (uint32_t)__builtin_bit_cast(uint16_t, h4) |
          ((uint32_t)__builtin_bit_cast(uint16_t, h5) << 16);
    o.w = (uint32_t)__builtin_bit_cast(uint16_t, h6) |
          ((uint32_t)__builtin_bit_cast(uint16_t, h7) << 16);
    *(uint4*)&outA[base] = o;
}

// -------- layer GEMM: 64r x 128c tile, BK=64 (2 chunks/iter, 16 MFMA/barrier) --------
__global__ __launch_bounds__(256, 3) void gemm_layer(
    const bf16* __restrict__ At, const bf16* __restrict__ Bt,
    const float* __restrict__ bias, bf16* __restrict__ hbOut,
    bf16* __restrict__ AtNext, int M, int KCh, int BX) {
    __shared__ bf16 lA[2][2][2048];
    __shared__ bf16 lB[2][2][4096];

    int nwg = gridDim.x;
    int q = nwg >> 3, r = nwg & 7;
    int p = blockIdx.x;
    int xcd = p & 7, slot = p >> 3;
    int L = (xcd < r ? xcd * (q + 1) : r * (q + 1) + (xcd - r) * q) + slot;
    int by = L / BX, bx = L % BX;

    int tid = threadIdx.x;
    int lane = tid & 63, w = tid >> 6;
    int wm = w >> 1, wn = w & 1;
    int lr = lane & 15, lg = lane >> 4;
    const bf16* Ab = At + (size_t)by * KCh * 2048;
    const bf16* Bb = Bt + (size_t)bx * KCh * 4096;

    f32x4 acc[2][4];
    #pragma unroll
    for (int i = 0; i < 2; i++)
        #pragma unroll
        for (int j = 0; j < 4; j++) {
            f32x4 z = {0.f, 0.f, 0.f, 0.f};
            acc[i][j] = z;
        }

    int u0 = tid, u1 = tid + 256;
    int offA = lg * 512 + (wm * 32 + lr) * 8;
    int offB = lg * 1024 + (wn * 64 + lr) * 8;

    #define LSTAGE(bufi, it)                                                      \
        do {                                                                      \
            const bf16* a0 = Ab + (size_t)(2 * (it)) * 2048;                      \
            const bf16* a1 = Ab + (size_t)(2 * (it) + 1) * 2048;                  \
            const bf16* b0 = Bb + (size_t)(2 * (it)) * 4096;                      \
            const bf16* b1 = Bb + (size_t)(2 * (it) + 1) * 4096;                  \
            gload16(a0 + tid * 8, &lA[bufi][0][tid * 8]);                         \
            gload16(a1 + tid * 8, &lA[bufi][1][tid * 8]);                         \
            gload16(b0 + u0 * 8, &lB[bufi][0][u0 * 8]);                           \
            gload16(b0 + u1 * 8, &lB[bufi][0][u1 * 8]);                           \
            gload16(b1 + u0 * 8, &lB[bufi][1][u0 * 8]);                           \
            gload16(b1 + u1 * 8, &lB[bufi][1][u1 * 8]);                           \
        } while (0)

    int NIT = KCh >> 1;
    LSTAGE(0, 0);
    __syncthreads();

    int buf = 0;
    for (int it = 0; it < NIT; it++) {
        if (it + 1 < NIT) LSTAGE(buf ^ 1, it + 1);
        #pragma unroll
        for (int kk = 0; kk < 2; kk++) {
            bf16x8 bh[4];
            #pragma unroll
            for (int n = 0; n < 4; n++)
                bh[n] = *(const bf16x8*)&lB[buf][kk][offB + n * 128];
            #pragma unroll
            for (int m = 0; m < 2; m++) {
                bf16x8 ah = *(const bf16x8*)&lA[buf][kk][offA + m * 128];
                #pragma unroll
                for (int n = 0; n < 4; n++)
                    acc[m][n] = __builtin_amdgcn_mfma_f32_16x16x32_bf16(
                        ah, bh[n], acc[m][n], 0, 0, 0);
            }
        }
        __syncthreads();
        buf ^= 1;
    }
    #undef LSTAGE

    int m0 = by * 64, n0 = bx * 128;
    #pragma unroll
    for (int m = 0; m < 2; m++) {
        #pragma unroll
        for (int n = 0; n < 4; n++) {
            int gr0 = m0 + wm * 32 + m * 16 + lg * 4;
            int gc = n0 + wn * 64 + n * 16 + lr;
            float bv = bias[gc];
            int cch = gc >> 5, g2 = (gc >> 3) & 3, j2 = gc & 7;
            #pragma unroll
            for (int r2 = 0; r2 < 4; r2++) {
                int grow = gr0 + r2;
                if (grow >= M) continue;
                float v = fmaxf(acc[m][n][r2] + bv, 0.f);
                bf16 hv = (bf16)v;
                if (hbOut) hbOut[(size_t)grow * 512 + gc] = hv;
                int panel = grow >> 6, row = grow & 63;
                AtNext[(size_t)panel * 32 * 2048 + (size_t)cch * 2048 +
                       g2 * 512 + row * 8 + j2] = hv;
            }
        }
    }
}

// -------- final GEMM: 64r x 128c tile, BK=64, 3 blocks/CU, f32 out + bias --------
__global__ __launch_bounds__(256, 3) void gemm_out(
    const bf16* __restrict__ At, const bf16* __restrict__ Bt,
    float* __restrict__ Fout, const float* __restrict__ bias,
    int M, int N, int KCh, int BX, int PANCH) {
    __shared__ bf16 lA[2][2][2048];
    __shared__ bf16 lB[2][2][4096];

    int nwg = gridDim.x;
    int q = nwg >> 3, r = nwg & 7;
    int p = blockIdx.x;
    int xcd = p & 7, slot = p >> 3;
    int L = (xcd < r ? xcd * (q + 1) : r * (q + 1) + (xcd - r) * q) + slot;
    int by = L / BX, bx = L % BX;

    int tid = threadIdx.x;
    int lane = tid & 63, w = tid >> 6;
    int wm = w >> 1, wn = w & 1;
    int lr = lane & 15, lg = lane >> 4;
    const bf16* Ab = At + (size_t)by * PANCH * 2048;   // chunks 0..KCh-1 = h plane
    const bf16* Bb = Bt + (size_t)bx * KCh * 4096;

    f32x4 acc[2][4];
    #pragma unroll
    for (int i = 0; i < 2; i++)
        #pragma unroll
        for (int j = 0; j < 4; j++) {
            f32x4 z = {0.f, 0.f, 0.f, 0.f};
            acc[i][j] = z;
        }

    int u0 = tid, u1 = tid + 256;
    int offA = lg * 512 + (wm * 32 + lr) * 8;
    int offB = lg * 1024 + (wn * 64 + lr) * 8;

    #define OSTAGE(bufi, it)                                                      \
        do {                                                                      \
            const bf16* a0 = Ab + (size_t)(2 * (it)) * 2048;                      \
            const bf16* a1 = Ab + (size_t)(2 * (it) + 1) * 2048;                  \
            const bf16* b0 = Bb + (size_t)(2 * (it)) * 4096;                      \
            const bf16* b1 = Bb + (size_t)(2 * (it) + 1) * 4096;                  \
            gload16(a0 + tid * 8, &lA[bufi][0][tid * 8]);                         \
            gload16(a1 + tid * 8, &lA[bufi][1][tid * 8]);                         \
            gload16(b0 + u0 * 8, &lB[bufi][0][u0 * 8]);                           \
            gload16(b0 + u1 * 8, &lB[bufi][0][u1 * 8]);                           \
            gload16(b1 + u0 * 8, &lB[bufi][1][u0 * 8]);                           \
            gload16(b1 + u1 * 8, &lB[bufi][1][u1 * 8]);                           \
        } while (0)

    int NIT = KCh >> 1;
    OSTAGE(0, 0);
    __syncthreads();
    int buf = 0;
    for (int it = 0; it < NIT; it++) {
        if (it + 1 < NIT) OSTAGE(buf ^ 1, it + 1);
        #pragma unroll
        for (int kk = 0; kk < 2; kk++) {
            bf16x8 bh[4];
            #pragma unroll
            for (int n = 0; n < 4; n++)
                bh[n] = *(const bf16x8*)&lB[buf][kk][offB + n * 128];
            #pragma unroll
            for (int m = 0; m < 2; m++) {
                bf16x8 ah = *(const bf16x8*)&lA[buf][kk][offA + m * 128];
                #pragma unroll
                for (int n = 0; n < 4; n++)
                    acc[m][n] = __builtin_amdgcn_mfma_f32_16x16x32_bf16(
                        ah, bh[n], acc[m][n], 0, 0, 0);
            }
        }
        __syncthreads();
        buf ^= 1;
    }
    #undef OSTAGE

    int m0 = by * 64, n0 = bx * 128;
    #pragma unroll
    for (int m = 0; m < 2; m++)
        #pragma unroll
        for (int n = 0; n < 4; n++) {
            int gr0 = m0 + wm * 32 + m * 16 + lg * 4;
            int gcol = n0 + wn * 64 + n * 16 + lr;
            if (gcol >= N) continue;
            float bv = bias[gcol];
            #pragma unroll
            for (int r2 = 0; r2 < 4; r2++) {
                int grow = gr0 + r2;
                if (grow < M) Fout[(size_t)grow * N + gcol] = acc[m][n][r2] + bv;
            }
        }
}

// ---------------- host launch ----------------
extern "C" void kernel_launch(void* const* d_in, const int* in_sizes, int n_in,
                              void* d_out, int out_size, void* d_ws, size_t ws_size,
                              hipStream_t stream) {
    const float* x  = (const float*)d_in[0];
    const int* src  = (const int*)d_in[1];
    const int* dst  = (const int*)d_in[2];
    const float* W1 = (const float*)d_in[3];
    const float* V1 = (const float*)d_in[4];
    const float* b1 = (const float*)d_in[5];
    const float* Wk = (const float*)d_in[6];
    const float* Vk = (const float*)d_in[7];
    const float* bk = (const float*)d_in[8];
    const float* Wd = (const float*)d_in[9];
    const float* bd = (const float*)d_in[10];

    // ws layout
    int* deg_out  = (int*)d_ws;
    int* deg_in   = deg_out + 10240;
    int* offsets  = deg_in + 10240;
    int* cursor   = offsets + 10240;
    int2* edge_pk = (int2*)(cursor + 10240);
    bf16* A_L1 = (bf16*)(edge_pk + NE);               // [158][16][2048]
    bf16* Am0  = A_L1 + (size_t)MPAN * 16 * 2048;     // [158][32][2048]
    bf16* Am1  = Am0 + (size_t)MPAN * 32 * 2048;      // [158][32][2048]
    bf16* B1t  = Am1 + (size_t)MPAN * 32 * 2048;      // [4][16][4096]
    bf16* Bkt  = B1t + (size_t)4 * 16 * 4096;         // [6][4][32][4096]
    bf16* Wdt  = Bkt + (size_t)6 * 4 * 32 * 4096;     // [12][16][4096]

    // d_out hosts the gather sources (all dead before gemm_out writes out)
    bf16* hb0 = (bf16*)d_out;                         // [NN][512]
    bf16* hb1 = hb0 + (size_t)NN * 512;
    bf16* xb  = hb1 + (size_t)NN * 512;               // [NN][256]
    float* out = (float*)d_out;

    hipMemsetAsync(deg_out, 0, 2 * 10240 * sizeof(int), stream);
    deg_kernel<<<(NE + 255) / 256, 256, 0, stream>>>(src, dst, deg_out, deg_in);
    scan_kernel<<<1, 1024, 0, stream>>>(deg_out, offsets, cursor);
    csr_kernel<<<(NE + 255) / 256, 256, 0, stream>>>(src, dst, deg_out, deg_in,
                                                     cursor, edge_pk);
    conv_fused<<<2442, 256, 0, stream>>>(x, xb, A_L1, V1, W1, B1t, Vk, Wk, Bkt,
                                         Wd, Wdt);

    dim3 blk(256);
    int glayer = MPAN * 4;        // 632 blocks
    int gout = MPAN * 12;         // 1896 blocks

    // layer 1: xagg -> A_L1 chunks 8-15; gemm K=512 (16 chunks, 8 iters)
    gather_agg<<<2 * 2500, blk, 0, stream>>>((const uint32_t*)xb, offsets, edge_pk,
                                             A_L1, 128, 1, 8, 16);
    gemm_layer<<<glayer, blk, 0, stream>>>(A_L1, B1t, b1, hb0, Am0, NN, 16, 4);

    for (int i = 0; i < 6; i++) {
        bf16* hcur = (i & 1) ? hb1 : hb0;
        bf16* hnxt = (i & 1) ? hb0 : hb1;
        bf16* Acur = (i & 1) ? Am1 : Am0;
        bf16* Anxt = (i & 1) ? Am0 : Am1;
        gather_agg8<<<2500, blk, 0, stream>>>((const uint4*)hcur, offsets,
                                              edge_pk, Acur);
        gemm_layer<<<glayer, blk, 0, stream>>>(Acur, Bkt + (size_t)i * 4 * 32 * 4096,
                                               bk + (size_t)i * CH,
                                               (i == 5) ? nullptr : hnxt, Anxt,
                                               NN, 32, 4);
    }

    // final: out = h @ Wd + bd (reads Am0 hi chunks 0-15, K=512)
    gemm_out<<<gout, blk, 0, stream>>>(Am0, Wdt, out, bd, NN, NL, 16, 12, 32);
}

// Round 20
// 379.223 us; speedup vs baseline: 1.0268x; 1.0268x over previous
//
#include <hip/hip_runtime.h>
#include <hip/hip_bf16.h>
#include <stdint.h>

#define NN 10000
#define NE 160000
#define INF 256
#define CH 512
#define NL 1440
#define MPAN 158   // ceil(10000/64) A panels (64-row)

typedef __bf16 bf16;
typedef __attribute__((ext_vector_type(8))) bf16 bf16x8;
typedef __attribute__((ext_vector_type(4))) float f32x4;

// A tiled layout: [panel(64 rows)][chunk(32 k')][g=4][row=64][j=8] (2048 elem/chunk)
// B tiled layout: [panel(128 cols)][chunk(32 k')][g=4][col=128][j=8] (4096 elem/chunk)
// Pure-bf16 associativity form: h' = relu([h | hagg] @ [V | W] + b)
//   mid: A 32 chunks (h 0-15, hagg 16-31);  L1: A 16 chunks (x 0-7, xagg 8-15).
// All GEMMs: 64r x 128c tile, BK=64 (2 chunks/iter), 48KB LDS, 3 blocks/CU.
// Mid gathers: 2 slices x 256 channels, uint2 (4 ch) per lane (r18 optimum).

__device__ __forceinline__ void gload16(const void* g, const void* l) {
    auto gp = reinterpret_cast<const __attribute__((address_space(1))) uint32_t*>(
        reinterpret_cast<uintptr_t>(g));
    auto lp = reinterpret_cast<__attribute__((address_space(3))) uint32_t*>(
        reinterpret_cast<uintptr_t>(l));
    __builtin_amdgcn_global_load_lds(gp, lp, 16, 0, 0);
}

// ---------------- graph prep ----------------
__global__ void deg_kernel(const int* __restrict__ src, const int* __restrict__ dst,
                           int* __restrict__ deg_out, int* __restrict__ deg_in) {
    int e = blockIdx.x * 256 + threadIdx.x;
    if (e < NE) {
        atomicAdd(&deg_out[src[e]], 1);
        atomicAdd(&deg_in[dst[e]], 1);
    }
}

__global__ __launch_bounds__(1024) void scan_kernel(const int* __restrict__ deg,
                                                    int* __restrict__ offsets,
                                                    int* __restrict__ cursor) {
    __shared__ int sums[1024];
    const int PER = 10;
    int tid = threadIdx.x;
    int base = tid * PER;
    int local[PER];
    int s = 0;
    #pragma unroll
    for (int i = 0; i < PER; i++) {
        int v = (base + i < NN) ? deg[base + i] : 0;
        local[i] = s;
        s += v;
    }
    sums[tid] = s;
    __syncthreads();
    for (int off = 1; off < 1024; off <<= 1) {
        int v = (tid >= off) ? sums[tid - off] : 0;
        __syncthreads();
        sums[tid] += v;
        __syncthreads();
    }
    int prev = (tid > 0) ? sums[tid - 1] : 0;
    #pragma unroll
    for (int i = 0; i < PER; i++) {
        if (base + i < NN) {
            int o = prev + local[i];
            offsets[base + i] = o;
            cursor[base + i] = o;
        }
    }
    if (tid == 0) offsets[NN] = sums[1023];
}

__global__ void csr_kernel(const int* __restrict__ src, const int* __restrict__ dst,
                           const int* __restrict__ deg_out, const int* __restrict__ deg_in,
                           int* __restrict__ cursor, int2* __restrict__ edge_pk) {
    int e = blockIdx.x * 256 + threadIdx.x;
    if (e < NE) {
        int s = src[e], d = dst[e];
        float dw = (float)max(deg_out[s], 1) * (float)max(deg_in[d], 1);
        float w = rsqrtf(dw);
        int pos = atomicAdd(&cursor[s], 1);
        edge_pk[pos] = make_int2(d, __float_as_int(w));
    }
}

// -------- fused conversions: x->(xb,A_L1) | V1W1 | VkWk | Wd --------
__global__ void conv_fused(const float* __restrict__ x, bf16* __restrict__ xb,
                           bf16* __restrict__ A_L1,
                           const float* __restrict__ V1, const float* __restrict__ W1,
                           bf16* __restrict__ B1t,
                           const float* __restrict__ Vk, const float* __restrict__ Wk,
                           bf16* __restrict__ Bkt,
                           const float* __restrict__ Wd, bf16* __restrict__ Wdt) {
    int b = blockIdx.x;
    int tid = threadIdx.x;
    if (b < 1250) {
        int idx = b * 256 + tid;
        if (idx >= NN * 32) return;
        int m = idx >> 5;
        int k8 = (idx & 31) * 8;
        const float* src = x + (size_t)m * INF + k8;
        float4 v0 = *(const float4*)src;
        float4 v1 = *(const float4*)(src + 4);
        bf16x8 o;
        o[0] = (bf16)v0.x; o[1] = (bf16)v0.y; o[2] = (bf16)v0.z; o[3] = (bf16)v0.w;
        o[4] = (bf16)v1.x; o[5] = (bf16)v1.y; o[6] = (bf16)v1.z; o[7] = (bf16)v1.w;
        *(bf16x8*)&xb[(size_t)idx * 8] = o;
        int panel = m >> 6, row = m & 63;
        int c = k8 >> 5, g = (k8 & 31) >> 3;
        *(bf16x8*)&A_L1[((size_t)panel * 16 + c) * 2048 + g * 512 + row * 8] = o;
    } else if (b < 1314) {
        int idx = (b - 1250) * 256 + tid;
        if (idx >= 512 * 32) return;
        int k8 = (idx >> 9) * 8;
        int n = idx & 511;
        bf16x8 vv, ww;
        #pragma unroll
        for (int j = 0; j < 8; j++) {
            vv[j] = (bf16)V1[(size_t)(k8 + j) * 512 + n];
            ww[j] = (bf16)W1[(size_t)(k8 + j) * 512 + n];
        }
        int panel = n >> 7, row = n & 127;
        int c = k8 >> 5, g = (k8 & 31) >> 3;
        size_t base = (size_t)panel * 16 * 4096 + g * 1024 + row * 8;
        *(bf16x8*)&B1t[base + (size_t)c * 4096] = vv;
        *(bf16x8*)&B1t[base + (size_t)(8 + c) * 4096] = ww;
    } else if (b < 2082) {
        int bb = b - 1314;
        int z = bb >> 7;
        int idx = (bb & 127) * 256 + tid;
        if (idx >= 512 * 64) return;
        const float* V = Vk + (size_t)z * CH * 512;
        const float* W = Wk + (size_t)z * CH * 512;
        bf16* out = Bkt + (size_t)z * 4 * 32 * 4096;
        int k8 = (idx >> 9) * 8;
        int n = idx & 511;
        bf16x8 vv, ww;
        #pragma unroll
        for (int j = 0; j < 8; j++) {
            vv[j] = (bf16)V[(size_t)(k8 + j) * 512 + n];
            ww[j] = (bf16)W[(size_t)(k8 + j) * 512 + n];
        }
        int panel = n >> 7, row = n & 127;
        int c = k8 >> 5, g = (k8 & 31) >> 3;
        size_t base = (size_t)panel * 32 * 4096 + g * 1024 + row * 8;
        *(bf16x8*)&out[base + (size_t)c * 4096] = vv;
        *(bf16x8*)&out[base + (size_t)(16 + c) * 4096] = ww;
    } else {
        int idx = (b - 2082) * 256 + tid;
        if (idx >= NL * 64) return;
        int k8 = (idx / NL) * 8;
        int n = idx % NL;
        bf16x8 hi;
        #pragma unroll
        for (int j = 0; j < 8; j++) hi[j] = (bf16)Wd[(size_t)(k8 + j) * NL + n];
        int panel = n >> 7, row = n & 127;
        int c = k8 >> 5, g = (k8 & 31) >> 3;
        size_t base = ((size_t)panel * 16) * 4096 + g * 1024 + row * 8;
        *(bf16x8*)&Wdt[base + (size_t)c * 4096] = hi;
    }
}

// ---- L1 gather: 2 slices x 128 ch, u32 (2 ch) per lane ----
__global__ __launch_bounds__(256) void gather_agg(
    const uint32_t* __restrict__ h32,
    const int* __restrict__ offsets,
    const int2* __restrict__ edge_pk,
    bf16* __restrict__ outA,
    int CHU, int SLOG, int CBASE, int PANCH) {
    int p = blockIdx.x;
    int slice = p & ((1 << SLOG) - 1);
    int grp = p >> SLOG;
    int wid = threadIdx.x >> 6;
    int lane = threadIdx.x & 63;
    int u = grp * 4 + wid;
    if (u >= NN) return;
    int c = slice * 128 + lane * 2;
    int cu = (slice << 6) + lane;

    int beg = offsets[u], end = offsets[u + 1];
    float a0 = 0.f, a1 = 0.f;
    int e = beg;
    for (; e + 7 < end; e += 8) {
        int2 pk[8];
        uint32_t qq[8];
        #pragma unroll
        for (int k = 0; k < 8; k++) pk[k] = edge_pk[e + k];
        #pragma unroll
        for (int k = 0; k < 8; k++) qq[k] = h32[pk[k].x * CHU + cu];
        #pragma unroll
        for (int k = 0; k < 8; k++) {
            float wt = __int_as_float(pk[k].y);
            a0 += wt * __uint_as_float(qq[k] << 16);
            a1 += wt * __uint_as_float(qq[k] & 0xffff0000u);
        }
    }
    for (; e + 3 < end; e += 4) {
        int2 pk[4];
        uint32_t qq[4];
        #pragma unroll
        for (int k = 0; k < 4; k++) pk[k] = edge_pk[e + k];
        #pragma unroll
        for (int k = 0; k < 4; k++) qq[k] = h32[pk[k].x * CHU + cu];
        #pragma unroll
        for (int k = 0; k < 4; k++) {
            float wt = __int_as_float(pk[k].y);
            a0 += wt * __uint_as_float(qq[k] << 16);
            a1 += wt * __uint_as_float(qq[k] & 0xffff0000u);
        }
    }
    for (; e < end; e++) {
        int2 pe = edge_pk[e];
        uint32_t qv = h32[pe.x * CHU + cu];
        float wt = __int_as_float(pe.y);
        a0 += wt * __uint_as_float(qv << 16);
        a1 += wt * __uint_as_float(qv & 0xffff0000u);
    }

    bf16 h0 = (bf16)a0, h1 = (bf16)a1;
    int row = u & 63, panel = u >> 6;
    int ch = CBASE + (c >> 5), g = (c >> 3) & 3, j = c & 7;
    size_t base = (size_t)panel * PANCH * 2048 + (size_t)ch * 2048 + g * 512 + row * 8 + j;
    uint32_t hw = (uint32_t)__builtin_bit_cast(uint16_t, h0) |
                  ((uint32_t)__builtin_bit_cast(uint16_t, h1) << 16);
    *(uint32_t*)&outA[base] = hw;
}

// ---- mid gather: 2 slices x 256 channels, uint2 (4 ch, 8B) per lane ----
__global__ __launch_bounds__(256) void gather_agg4(
    const uint2* __restrict__ h64,   // row-major bf16 pairs, 128 uint2 per row
    const int* __restrict__ offsets,
    const int2* __restrict__ edge_pk,
    bf16* __restrict__ outA) {       // 32-chunk panels, hagg at chunks 16..31
    int p = blockIdx.x;
    int slice = p & 1;
    int grp = p >> 1;
    int wid = threadIdx.x >> 6;
    int lane = threadIdx.x & 63;
    int u = grp * 4 + wid;
    if (u >= NN) return;
    int c = slice * 256 + lane * 4;          // 4 consecutive channels
    int cu = (slice << 6) + lane;            // uint2 index within 128-uint2 row

    int beg = offsets[u], end = offsets[u + 1];
    float a0 = 0.f, a1 = 0.f, a2 = 0.f, a3 = 0.f;
    int e = beg;
    for (; e + 7 < end; e += 8) {
        int2 pk[8];
        uint2 qq[8];
        #pragma unroll
        for (int k = 0; k < 8; k++) pk[k] = edge_pk[e + k];
        #pragma unroll
        for (int k = 0; k < 8; k++) qq[k] = h64[pk[k].x * 128 + cu];
        #pragma unroll
        for (int k = 0; k < 8; k++) {
            float wt = __int_as_float(pk[k].y);
            a0 += wt * __uint_as_float(qq[k].x << 16);
            a1 += wt * __uint_as_float(qq[k].x & 0xffff0000u);
            a2 += wt * __uint_as_float(qq[k].y << 16);
            a3 += wt * __uint_as_float(qq[k].y & 0xffff0000u);
        }
    }
    for (; e + 3 < end; e += 4) {
        int2 pk[4];
        uint2 qq[4];
        #pragma unroll
        for (int k = 0; k < 4; k++) pk[k] = edge_pk[e + k];
        #pragma unroll
        for (int k = 0; k < 4; k++) qq[k] = h64[pk[k].x * 128 + cu];
        #pragma unroll
        for (int k = 0; k < 4; k++) {
            float wt = __int_as_float(pk[k].y);
            a0 += wt * __uint_as_float(qq[k].x << 16);
            a1 += wt * __uint_as_float(qq[k].x & 0xffff0000u);
            a2 += wt * __uint_as_float(qq[k].y << 16);
            a3 += wt * __uint_as_float(qq[k].y & 0xffff0000u);
        }
    }
    for (; e < end; e++) {
        int2 pe = edge_pk[e];
        uint2 qv = h64[pe.x * 128 + cu];
        float wt = __int_as_float(pe.y);
        a0 += wt * __uint_as_float(qv.x << 16);
        a1 += wt * __uint_as_float(qv.x & 0xffff0000u);
        a2 += wt * __uint_as_float(qv.y << 16);
        a3 += wt * __uint_as_float(qv.y & 0xffff0000u);
    }

    bf16 h0 = (bf16)a0, h1 = (bf16)a1, h2 = (bf16)a2, h3 = (bf16)a3;
    int row = u & 63, panel = u >> 6;
    int ch = 16 + (c >> 5), g = (c >> 3) & 3, j = c & 7;   // j in {0,4}
    size_t base = (size_t)panel * 32 * 2048 + (size_t)ch * 2048 + g * 512 + row * 8 + j;
    uint32_t hw0 = (uint32_t)__builtin_bit_cast(uint16_t, h0) |
                   ((uint32_t)__builtin_bit_cast(uint16_t, h1) << 16);
    uint32_t hw1 = (uint32_t)__builtin_bit_cast(uint16_t, h2) |
                   ((uint32_t)__builtin_bit_cast(uint16_t, h3) << 16);
    *(uint2*)&outA[base] = make_uint2(hw0, hw1);
}

// -------- layer GEMM: 64r x 128c tile, BK=64 (2 chunks/iter, 16 MFMA/barrier) --------
__global__ __launch_bounds__(256, 3) void gemm_layer(
    const bf16* __restrict__ At, const bf16* __restrict__ Bt,
    const float* __restrict__ bias, bf16* __restrict__ hbOut,
    bf16* __restrict__ AtNext, int M, int KCh, int BX) {
    __shared__ bf16 lA[2][2][2048];
    __shared__ bf16 lB[2][2][4096];

    int nwg = gridDim.x;
    int q = nwg >> 3, r = nwg & 7;
    int p = blockIdx.x;
    int xcd = p & 7, slot = p >> 3;
    int L = (xcd < r ? xcd * (q + 1) : r * (q + 1) + (xcd - r) * q) + slot;
    int by = L / BX, bx = L % BX;

    int tid = threadIdx.x;
    int lane = tid & 63, w = tid >> 6;
    int wm = w >> 1, wn = w & 1;
    int lr = lane & 15, lg = lane >> 4;
    const bf16* Ab = At + (size_t)by * KCh * 2048;
    const bf16* Bb = Bt + (size_t)bx * KCh * 4096;

    f32x4 acc[2][4];
    #pragma unroll
    for (int i = 0; i < 2; i++)
        #pragma unroll
        for (int j = 0; j < 4; j++) {
            f32x4 z = {0.f, 0.f, 0.f, 0.f};
            acc[i][j] = z;
        }

    int u0 = tid, u1 = tid + 256;
    int offA = lg * 512 + (wm * 32 + lr) * 8;
    int offB = lg * 1024 + (wn * 64 + lr) * 8;

    #define LSTAGE(bufi, it)                                                      \
        do {                                                                      \
            const bf16* a0 = Ab + (size_t)(2 * (it)) * 2048;                      \
            const bf16* a1 = Ab + (size_t)(2 * (it) + 1) * 2048;                  \
            const bf16* b0 = Bb + (size_t)(2 * (it)) * 4096;                      \
            const bf16* b1 = Bb + (size_t)(2 * (it) + 1) * 4096;                  \
            gload16(a0 + tid * 8, &lA[bufi][0][tid * 8]);                         \
            gload16(a1 + tid * 8, &lA[bufi][1][tid * 8]);                         \
            gload16(b0 + u0 * 8, &lB[bufi][0][u0 * 8]);                           \
            gload16(b0 + u1 * 8, &lB[bufi][0][u1 * 8]);                           \
            gload16(b1 + u0 * 8, &lB[bufi][1][u0 * 8]);                           \
            gload16(b1 + u1 * 8, &lB[bufi][1][u1 * 8]);                           \
        } while (0)

    int NIT = KCh >> 1;
    LSTAGE(0, 0);
    __syncthreads();

    int buf = 0;
    for (int it = 0; it < NIT; it++) {
        if (it + 1 < NIT) LSTAGE(buf ^ 1, it + 1);
        #pragma unroll
        for (int kk = 0; kk < 2; kk++) {
            bf16x8 bh[4];
            #pragma unroll
            for (int n = 0; n < 4; n++)
                bh[n] = *(const bf16x8*)&lB[buf][kk][offB + n * 128];
            #pragma unroll
            for (int m = 0; m < 2; m++) {
                bf16x8 ah = *(const bf16x8*)&lA[buf][kk][offA + m * 128];
                #pragma unroll
                for (int n = 0; n < 4; n++)
                    acc[m][n] = __builtin_amdgcn_mfma_f32_16x16x32_bf16(
                        ah, bh[n], acc[m][n], 0, 0, 0);
            }
        }
        __syncthreads();
        buf ^= 1;
    }
    #undef LSTAGE

    int m0 = by * 64, n0 = bx * 128;
    #pragma unroll
    for (int m = 0; m < 2; m++) {
        #pragma unroll
        for (int n = 0; n < 4; n++) {
            int gr0 = m0 + wm * 32 + m * 16 + lg * 4;
            int gc = n0 + wn * 64 + n * 16 + lr;
            float bv = bias[gc];
            int cch = gc >> 5, g2 = (gc >> 3) & 3, j2 = gc & 7;
            #pragma unroll
            for (int r2 = 0; r2 < 4; r2++) {
                int grow = gr0 + r2;
                if (grow >= M) continue;
                float v = fmaxf(acc[m][n][r2] + bv, 0.f);
                bf16 hv = (bf16)v;
                if (hbOut) hbOut[(size_t)grow * 512 + gc] = hv;
                int panel = grow >> 6, row = grow & 63;
                AtNext[(size_t)panel * 32 * 2048 + (size_t)cch * 2048 +
                       g2 * 512 + row * 8 + j2] = hv;
            }
        }
    }
}

// -------- final GEMM: 64r x 128c tile, BK=64, 3 blocks/CU, f32 out + bias --------
__global__ __launch_bounds__(256, 3) void gemm_out(
    const bf16* __restrict__ At, const bf16* __restrict__ Bt,
    float* __restrict__ Fout, const float* __restrict__ bias,
    int M, int N, int KCh, int BX, int PANCH) {
    __shared__ bf16 lA[2][2][2048];
    __shared__ bf16 lB[2][2][4096];

    int nwg = gridDim.x;
    int q = nwg >> 3, r = nwg & 7;
    int p = blockIdx.x;
    int xcd = p & 7, slot = p >> 3;
    int L = (xcd < r ? xcd * (q + 1) : r * (q + 1) + (xcd - r) * q) + slot;
    int by = L / BX, bx = L % BX;

    int tid = threadIdx.x;
    int lane = tid & 63, w = tid >> 6;
    int wm = w >> 1, wn = w & 1;
    int lr = lane & 15, lg = lane >> 4;
    const bf16* Ab = At + (size_t)by * PANCH * 2048;   // chunks 0..KCh-1 = h plane
    const bf16* Bb = Bt + (size_t)bx * KCh * 4096;

    f32x4 acc[2][4];
    #pragma unroll
    for (int i = 0; i < 2; i++)
        #pragma unroll
        for (int j = 0; j < 4; j++) {
            f32x4 z = {0.f, 0.f, 0.f, 0.f};
            acc[i][j] = z;
        }

    int u0 = tid, u1 = tid + 256;
    int offA = lg * 512 + (wm * 32 + lr) * 8;
    int offB = lg * 1024 + (wn * 64 + lr) * 8;

    #define OSTAGE(bufi, it)                                                      \
        do {                                                                      \
            const bf16* a0 = Ab + (size_t)(2 * (it)) * 2048;                      \
            const bf16* a1 = Ab + (size_t)(2 * (it) + 1) * 2048;                  \
            const bf16* b0 = Bb + (size_t)(2 * (it)) * 4096;                      \
            const bf16* b1 = Bb + (size_t)(2 * (it) + 1) * 4096;                  \
            gload16(a0 + tid * 8, &lA[bufi][0][tid * 8]);                         \
            gload16(a1 + tid * 8, &lA[bufi][1][tid * 8]);                         \
            gload16(b0 + u0 * 8, &lB[bufi][0][u0 * 8]);                           \
            gload16(b0 + u1 * 8, &lB[bufi][0][u1 * 8]);                           \
            gload16(b1 + u0 * 8, &lB[bufi][1][u0 * 8]);                           \
            gload16(b1 + u1 * 8, &lB[bufi][1][u1 * 8]);                           \
        } while (0)

    int NIT = KCh >> 1;
    OSTAGE(0, 0);
    __syncthreads();
    int buf = 0;
    for (int it = 0; it < NIT; it++) {
        if (it + 1 < NIT) OSTAGE(buf ^ 1, it + 1);
        #pragma unroll
        for (int kk = 0; kk < 2; kk++) {
            bf16x8 bh[4];
            #pragma unroll
            for (int n = 0; n < 4; n++)
                bh[n] = *(const bf16x8*)&lB[buf][kk][offB + n * 128];
            #pragma unroll
            for (int m = 0; m < 2; m++) {
                bf16x8 ah = *(const bf16x8*)&lA[buf][kk][offA + m * 128];
                #pragma unroll
                for (int n = 0; n < 4; n++)
                    acc[m][n] = __builtin_amdgcn_mfma_f32_16x16x32_bf16(
                        ah, bh[n], acc[m][n], 0, 0, 0);
            }
        }
        __syncthreads();
        buf ^= 1;
    }
    #undef OSTAGE

    int m0 = by * 64, n0 = bx * 128;
    #pragma unroll
    for (int m = 0; m < 2; m++)
        #pragma unroll
        for (int n = 0; n < 4; n++) {
            int gr0 = m0 + wm * 32 + m * 16 + lg * 4;
            int gcol = n0 + wn * 64 + n * 16 + lr;
            if (gcol >= N) continue;
            float bv = bias[gcol];
            #pragma unroll
            for (int r2 = 0; r2 < 4; r2++) {
                int grow = gr0 + r2;
                if (grow < M) Fout[(size_t)grow * N + gcol] = acc[m][n][r2] + bv;
            }
        }
}

// ---------------- host launch ----------------
extern "C" void kernel_launch(void* const* d_in, const int* in_sizes, int n_in,
                              void* d_out, int out_size, void* d_ws, size_t ws_size,
                              hipStream_t stream) {
    const float* x  = (const float*)d_in[0];
    const int* src  = (const int*)d_in[1];
    const int* dst  = (const int*)d_in[2];
    const float* W1 = (const float*)d_in[3];
    const float* V1 = (const float*)d_in[4];
    const float* b1 = (const float*)d_in[5];
    const float* Wk = (const float*)d_in[6];
    const float* Vk = (const float*)d_in[7];
    const float* bk = (const float*)d_in[8];
    const float* Wd = (const float*)d_in[9];
    const float* bd = (const float*)d_in[10];

    // ws layout
    int* deg_out  = (int*)d_ws;
    int* deg_in   = deg_out + 10240;
    int* offsets  = deg_in + 10240;
    int* cursor   = offsets + 10240;
    int2* edge_pk = (int2*)(cursor + 10240);
    bf16* A_L1 = (bf16*)(edge_pk + NE);               // [158][16][2048]
    bf16* Am0  = A_L1 + (size_t)MPAN * 16 * 2048;     // [158][32][2048]
    bf16* Am1  = Am0 + (size_t)MPAN * 32 * 2048;      // [158][32][2048]
    bf16* B1t  = Am1 + (size_t)MPAN * 32 * 2048;      // [4][16][4096]
    bf16* Bkt  = B1t + (size_t)4 * 16 * 4096;         // [6][4][32][4096]
    bf16* Wdt  = Bkt + (size_t)6 * 4 * 32 * 4096;     // [12][16][4096]

    // d_out hosts the gather sources (all dead before gemm_out writes out)
    bf16* hb0 = (bf16*)d_out;                         // [NN][512]
    bf16* hb1 = hb0 + (size_t)NN * 512;
    bf16* xb  = hb1 + (size_t)NN * 512;               // [NN][256]
    float* out = (float*)d_out;

    hipMemsetAsync(deg_out, 0, 2 * 10240 * sizeof(int), stream);
    deg_kernel<<<(NE + 255) / 256, 256, 0, stream>>>(src, dst, deg_out, deg_in);
    scan_kernel<<<1, 1024, 0, stream>>>(deg_out, offsets, cursor);
    csr_kernel<<<(NE + 255) / 256, 256, 0, stream>>>(src, dst, deg_out, deg_in,
                                                     cursor, edge_pk);
    conv_fused<<<2442, 256, 0, stream>>>(x, xb, A_L1, V1, W1, B1t, Vk, Wk, Bkt,
                                         Wd, Wdt);

    dim3 blk(256);
    int glayer = MPAN * 4;        // 632 blocks
    int gout = MPAN * 12;         // 1896 blocks

    // layer 1: xagg -> A_L1 chunks 8-15; gemm K=512 (16 chunks, 8 iters)
    gather_agg<<<2 * 2500, blk, 0, stream>>>((const uint32_t*)xb, offsets, edge_pk,
                                             A_L1, 128, 1, 8, 16);
    gemm_layer<<<glayer, blk, 0, stream>>>(A_L1, B1t, b1, hb0, Am0, NN, 16, 4);

    for (int i = 0; i < 6; i++) {
        bf16* hcur = (i & 1) ? hb1 : hb0;
        bf16* hnxt = (i & 1) ? hb0 : hb1;
        bf16* Acur = (i & 1) ? Am1 : Am0;
        bf16* Anxt = (i & 1) ? Am0 : Am1;
        gather_agg4<<<2 * 2500, blk, 0, stream>>>((const uint2*)hcur, offsets,
                                                  edge_pk, Acur);
        gemm_layer<<<glayer, blk, 0, stream>>>(Acur, Bkt + (size_t)i * 4 * 32 * 4096,
                                               bk + (size_t)i * CH,
                                               (i == 5) ? nullptr : hnxt, Anxt,
                                               NN, 32, 4);
    }

    // final: out = h @ Wd + bd (reads Am0 hi chunks 0-15, K=512)
    gemm_out<<<gout, blk, 0, stream>>>(Am0, Wdt, out, bd, NN, NL, 16, 12, 32);
}